// Round 16
// baseline (41.206 us; speedup 1.0000x reference)
//
#include <hip/hip_runtime.h>
#include <hip/hip_bf16.h>
#include <math.h>

#define D 32
#define CAP 28      // Gram-path capacity (P(Poisson(8)>28)~1e-9/class); exact fallback beyond
#define CPB 4       // classes (=waves) per block
#define SBT 512     // k_score threads (8 waves)
#define SSM 16      // samples per k_score block

typedef __attribute__((ext_vector_type(8))) short short8v;
typedef __attribute__((ext_vector_type(4))) float float4v;

static __device__ __forceinline__ unsigned short f2bf(float f) {
    union { __hip_bfloat16 h; unsigned short u; } cv;
    cv.h = __float2bfloat16(f);
    return cv.u;
}
static __device__ __forceinline__ short8v cvt8(float4 u0, float4 u1) {
    short8v o;
    o[0] = (short)f2bf(u0.x); o[1] = (short)f2bf(u0.y);
    o[2] = (short)f2bf(u0.z); o[3] = (short)f2bf(u0.w);
    o[4] = (short)f2bf(u1.x); o[5] = (short)f2bf(u1.y);
    o[6] = (short)f2bf(u1.z); o[7] = (short)f2bf(u1.w);
    return o;
}

// ---- K1: bucket + MFMA Gram + rolled prefix-product recurrence -> qb, w ----
// 512 blocks x 4 waves; wave owns one class. u_k = B_k*(P + sum_j gamma_j r_j):
// gamma_j written ONCE (no O(n^2) rescale); all loops rolled (small code, I$-friendly).
__global__ void __launch_bounds__(64 * CPB)
k_gram(const float* __restrict__ x, const int* __restrict__ tgt,
       const float* __restrict__ p_in, const float* __restrict__ kw,
       unsigned short* __restrict__ qb, float* __restrict__ w,
       int N, int C, float dval) {
    __shared__ int   lcnt[CPB];
    __shared__ int   llist[CPB][CAP];
    __shared__ int   slist[CPB][CAP];
    __shared__ float Graw[CPB][32][33];   // raw-row Gram; row 31 = P
    __shared__ float invv[CPB][32];       // 1/max(||r_i||,1e-12)
    __shared__ float gamS[CPB][CAP];      // gamma coefficients
    int tid = threadIdx.x, b = blockIdx.x;
    int lane = tid & 63, wv = tid >> 6;
    int c = b * CPB + wv, e = lane & 31;

    // ---- Phase A: block-local bucket of its 4 classes (LDS atomics) ----
    if (tid < CPB) lcnt[tid] = 0;
    __syncthreads();
    for (int i = tid; i < N; i += 64 * CPB) {
        int r = tgt[i] - b * CPB;
        if ((unsigned)r < (unsigned)CPB) {
            int pos = atomicAdd(&lcnt[r], 1);
            if (pos < CAP) llist[r][pos] = i;
        }
    }
    __syncthreads();

    int n = lcnt[wv];
    float kap = fmaxf(kw[c], 0.0f);

    if (n <= CAP) {
        // ---- Phase B: rank-sort indices (ascending) into slist, rolled ----
        int idx = (lane < n) ? llist[wv][lane] : 0x7fffffff;
        int rank = 0;
        for (int j = 0; j < n; ++j) { int v = __shfl(idx, j); rank += (v < idx) ? 1 : 0; }
        if (lane < n) slist[wv][rank] = idx;

        // ---- Phase C: fragment gather (rows 0..n-1 raw samples, 31 raw P) + 4 MFMAs ----
        int m = lane & 15, kg = lane >> 4, k0 = kg * 8;
        short8v A0 = {0,0,0,0,0,0,0,0}, A1 = {0,0,0,0,0,0,0,0};
        if (m < n) {
            const float4* px = (const float4*)(x + (size_t)slist[wv][m] * D + k0);
            A0 = cvt8(px[0], px[1]);
        }
        {
            int r = 16 + m;
            if (r < n) {
                const float4* px = (const float4*)(x + (size_t)slist[wv][r] * D + k0);
                A1 = cvt8(px[0], px[1]);
            } else if (r == 31) {
                const float4* px = (const float4*)(p_in + (size_t)c * D + k0);
                A1 = cvt8(px[0], px[1]);
            }
        }
        float4v z = {0.f, 0.f, 0.f, 0.f};
        float4v g00 = __builtin_amdgcn_mfma_f32_16x16x32_bf16(A0, A0, z, 0, 0, 0);
        float4v g01 = __builtin_amdgcn_mfma_f32_16x16x32_bf16(A0, A1, z, 0, 0, 0);
        float4v g10 = __builtin_amdgcn_mfma_f32_16x16x32_bf16(A1, A0, z, 0, 0, 0);
        float4v g11 = __builtin_amdgcn_mfma_f32_16x16x32_bf16(A1, A1, z, 0, 0, 0);
#pragma unroll
        for (int r = 0; r < 4; ++r) {          // C/D: row=(lane>>4)*4+r, col=lane&15
            int rr = kg * 4 + r;
            Graw[wv][rr][m]           = g00[r];
            Graw[wv][rr][16 + m]      = g01[r];
            Graw[wv][16 + rr][m]      = g10[r];
            Graw[wv][16 + rr][16 + m] = g11[r];
        }
        if (lane < 32)
            invv[wv][lane] = 1.0f / fmaxf(sqrtf(Graw[wv][lane][lane]), 1e-12f);

        // ---- Phase D: rolled scalar recurrence (replicated on lanes) ----
        // m_k^2 = .0025 + .9025*U2 + .095*<s_k,u_k>;  <s_k,u_k> = invv_k*B_k*dot
        float B = 1.0f, U2 = Graw[wv][31][31];
        for (int kk = 0; kk < n; ++kk) {
            const float* grow = &Graw[wv][kk][0];
            float a0 = 0.f, a1 = 0.f, a2 = 0.f, a3 = 0.f;
            int j = 0;
            for (; j + 4 <= kk; j += 4) {
                a0 = fmaf(gamS[wv][j],     grow[j],     a0);
                a1 = fmaf(gamS[wv][j + 1], grow[j + 1], a1);
                a2 = fmaf(gamS[wv][j + 2], grow[j + 2], a2);
                a3 = fmaf(gamS[wv][j + 3], grow[j + 3], a3);
            }
            for (; j < kk; ++j) a0 = fmaf(gamS[wv][j], grow[j], a0);
            float dot = grow[31] + ((a0 + a1) + (a2 + a3));
            float dsum = invv[wv][kk] * B * dot;
            float m2 = 0.0025f + fmaf(0.9025f, U2, 0.095f * dsum);
            float mm = fmaxf(sqrtf(m2), 1e-12f);
            B *= 0.95f / mm;                        // B_{k+1}
            float gk = (0.05f * invv[wv][kk]) / (mm * B);
            if (lane == 0) gamS[wv][kk] = gk;
            U2 = 1.0f;
        }

        // ---- Phase E: direction u = P + sum gamma_j r_j (B_n killed by cosine-norm) ----
        float u = p_in[(size_t)c * D + e];
        for (int j = 0; j < n; ++j)
            u = fmaf(gamS[wv][j], x[(size_t)slist[wv][j] * D + e], u);
        float ss = u * u;
        ss += __shfl_xor(ss, 16); ss += __shfl_xor(ss, 8); ss += __shfl_xor(ss, 4);
        ss += __shfl_xor(ss, 2);  ss += __shfl_xor(ss, 1);
        float pninv = 1.0f / fmaxf(sqrtf(ss), 1e-8f);
        if (lane < D) qb[(size_t)c * D + e] = f2bf(kap * pninv * u);
    } else {
        // ---- exact fallback (statistically never): ordered ballot-scan chain ----
        float p = p_in[(size_t)c * D + e];
        for (int ii = 0; ii < N; ii += 64) {
            unsigned long long mb = __ballot(tgt[ii + lane] == c);
            while (mb) {
                int j = __ffsll(mb) - 1;
                mb &= (mb - 1);
                float v = x[(size_t)(ii + j) * D + e];
                float s2 = v * v;
                s2 += __shfl_xor(s2, 16); s2 += __shfl_xor(s2, 8); s2 += __shfl_xor(s2, 4);
                s2 += __shfl_xor(s2, 2);  s2 += __shfl_xor(s2, 1);
                float s = v / fmaxf(sqrtf(s2), 1e-12f);
                p = fmaf(0.05f, s, 0.95f * p);
                float pp = p * p;
                pp += __shfl_xor(pp, 16); pp += __shfl_xor(pp, 8); pp += __shfl_xor(pp, 4);
                pp += __shfl_xor(pp, 2);  pp += __shfl_xor(pp, 1);
                p = p / fmaxf(sqrtf(pp), 1e-12f);
            }
        }
        float pp = p * p;
        pp += __shfl_xor(pp, 16); pp += __shfl_xor(pp, 8); pp += __shfl_xor(pp, 4);
        pp += __shfl_xor(pp, 2);  pp += __shfl_xor(pp, 1);
        float pn = p / fmaxf(sqrtf(pp), 1e-8f);
        if (lane < D) qb[(size_t)c * D + e] = f2bf(kap * pn);
    }

    if (lane == 0) {
        // log C_d(kap), cancellation-free rearrangement
        float nu = 0.5f * dval - 1.0f;
        float zz = kap / nu, z2 = zz * zz;
        float sq = sqrtf(1.0f + z2);
        float t  = 1.0f / sq;
        float u1 = (3.0f * t - 5.0f * t * t * t) * (1.0f / 24.0f);
        float lw = dval * (-0.918938533204672742f)
                 + nu * (logf(nu) + log1pf(sq) - sq)
                 + 0.5f * logf(6.2831853071795864f * nu)
                 + 0.25f * log1pf(z2)
                 - log1pf(u1 / nu);
        w[c] = __expf(lw);
    }
}

// ---- K2: per-block full-row MFMA + exp rowsum + target-logit capture + NLL ----
// (unchanged, verified) 1024 blocks x 8 waves; block owns 16 samples.
__global__ void __launch_bounds__(SBT)
k_score(const float* __restrict__ x, const int* __restrict__ tgt,
        const unsigned short* __restrict__ qb, const float* __restrict__ w,
        float* __restrict__ part, int N, int C) {
    __shared__ float Sl[8][SSM];
    __shared__ float Lt[SSM];
    int tid = threadIdx.x, b = blockIdx.x;
    int lane = tid & 63, wv = tid >> 6;
    int m = lane & 15, kg = lane >> 4, k0 = kg * 8;
    int s0 = b * SSM;

    short8v a0;
    {
        const float4* px = (const float4*)(x + (size_t)(s0 + m) * D + k0);
        float4 u0 = px[0], u1 = px[1];
        float ss = u0.x*u0.x + u0.y*u0.y + u0.z*u0.z + u0.w*u0.w
                 + u1.x*u1.x + u1.y*u1.y + u1.z*u1.z + u1.w*u1.w;
        ss += __shfl_xor(ss, 16); ss += __shfl_xor(ss, 32);
        float inv = 1.0f / fmaxf(sqrtf(ss), 1e-8f);
        float4 v0, v1;
        v0.x = u0.x*inv; v0.y = u0.y*inv; v0.z = u0.z*inv; v0.w = u0.w*inv;
        v1.x = u1.x*inv; v1.y = u1.y*inv; v1.z = u1.z*inv; v1.w = u1.w*inv;
        a0 = cvt8(v0, v1);
    }

    int tr0[4];
#pragma unroll
    for (int r = 0; r < 4; ++r) tr0[r] = tgt[s0 + kg * 4 + r];

    float4v z = {0.f, 0.f, 0.f, 0.f};
    float4v sa0 = z;
    int ntiles = C >> 7;
    for (int jt = 0; jt < ntiles; ++jt) {
        int c0 = (wv * ntiles + jt) * 16;
        short8v bfrag = *(const short8v*)(qb + (size_t)(c0 + m) * D + k0);
        float wl = w[c0 + m];
        float4v acc0 = __builtin_amdgcn_mfma_f32_16x16x32_bf16(a0, bfrag, z, 0, 0, 0);
#pragma unroll
        for (int r = 0; r < 4; ++r) {
            if (c0 + m == tr0[r]) Lt[kg * 4 + r] = acc0[r];
            sa0[r] = fmaf(wl, __expf(acc0[r]), sa0[r]);
        }
    }
#pragma unroll
    for (int off = 1; off < 16; off <<= 1) {
#pragma unroll
        for (int r = 0; r < 4; ++r) sa0[r] += __shfl_xor(sa0[r], off);
    }
    if (m == 0) {
#pragma unroll
        for (int r = 0; r < 4; ++r) Sl[wv][kg * 4 + r] = sa0[r];
    }
    __syncthreads();

    if (wv == 0) {
        float val = 0.f;
        if (lane < SSM) {
            int s = lane;
            float S = ((Sl[0][s] + Sl[1][s]) + (Sl[2][s] + Sl[3][s]))
                    + ((Sl[4][s] + Sl[5][s]) + (Sl[6][s] + Sl[7][s]));
            int t = tgt[s0 + s];
            val = logf(w[t] * __expf(Lt[s]) / S + 1e-6f);
        }
        val += __shfl_xor(val, 32); val += __shfl_xor(val, 16); val += __shfl_xor(val, 8);
        val += __shfl_xor(val, 4);  val += __shfl_xor(val, 2);  val += __shfl_xor(val, 1);
        if (lane == 0) part[b] = val;
    }
}

// ---- K3: deterministic fixed-order final reduce (1 block, 1024 partials) ----
__global__ void k_out(const float* __restrict__ part, float* __restrict__ out,
                      int N, int nblk) {
    __shared__ float red[8];
    int tid = threadIdx.x, lane = tid & 63, wv = tid >> 6;
    float v = 0.f;
    if (tid < nblk)       v += part[tid];
    if (tid + 512 < nblk) v += part[tid + 512];
    v += __shfl_xor(v, 32); v += __shfl_xor(v, 16); v += __shfl_xor(v, 8);
    v += __shfl_xor(v, 4);  v += __shfl_xor(v, 2);  v += __shfl_xor(v, 1);
    if (lane == 0) red[wv] = v;
    __syncthreads();
    if (tid == 0)
        out[0] = -(((red[0] + red[1]) + (red[2] + red[3]))
                 + ((red[4] + red[5]) + (red[6] + red[7]))) / (float)N;
}

extern "C" void kernel_launch(void* const* d_in, const int* in_sizes, int n_in,
                              void* d_out, int out_size, void* d_ws, size_t ws_size,
                              hipStream_t stream) {
    const float* x    = (const float*)d_in[0];   // [N, D]
    const float* kw   = (const float*)d_in[1];   // [C]
    const float* p_in = (const float*)d_in[2];   // [C, D]
    const int*   tgt  = (const int*)d_in[3];     // [N]
    int C = in_sizes[1];
    int N = in_sizes[3];
    float dval = (float)(in_sizes[2] / C);       // == 32
    int nblk = N / SSM;                           // 1024 score blocks

    // ws layout: qb | w | part
    unsigned short* qb = (unsigned short*)d_ws;            // C*D bf16
    float* w    = (float*)(qb + (size_t)C * D);            // C f32
    float* part = w + C;                                   // nblk f32
    (void)n_in; (void)out_size; (void)ws_size;

    // node 1: bucket + MFMA-Gram rolled-recurrence solve -> qb, w
    k_gram<<<C / CPB, 64 * CPB, 0, stream>>>(x, tgt, p_in, kw, qb, w, N, C, dval);
    // node 2: full-row score + NLL partials
    k_score<<<nblk, SBT, 0, stream>>>(x, tgt, qb, w, part, N, C);
    // node 3: final reduce
    k_out<<<1, 512, 0, stream>>>(part, (float*)d_out, N, nblk);
}

// Round 17
// 40.752 us; speedup vs baseline: 1.0112x; 1.0112x over previous
//
#include <hip/hip_runtime.h>
#include <hip/hip_bf16.h>
#include <math.h>

#define D 32
#define CAP 28      // Gram-path capacity (P(Poisson(8)>28)~1e-9/class); exact fallback beyond
#define CPB 4       // classes (=waves) per block
#define SBT 512     // k_score threads (8 waves)
#define SSM 16      // samples per k_score block

typedef __attribute__((ext_vector_type(8))) short short8v;
typedef __attribute__((ext_vector_type(4))) float float4v;

static __device__ __forceinline__ unsigned short f2bf(float f) {
    union { __hip_bfloat16 h; unsigned short u; } cv;
    cv.h = __float2bfloat16(f);
    return cv.u;
}
static __device__ __forceinline__ float bf2f(unsigned short u) {
    union { float f; unsigned int i; } c;
    c.i = ((unsigned int)u) << 16;
    return c.f;
}
static __device__ __forceinline__ short8v cvt8(float4 u0, float4 u1) {
    short8v o;
    o[0] = (short)f2bf(u0.x); o[1] = (short)f2bf(u0.y);
    o[2] = (short)f2bf(u0.z); o[3] = (short)f2bf(u0.w);
    o[4] = (short)f2bf(u1.x); o[5] = (short)f2bf(u1.y);
    o[6] = (short)f2bf(u1.z); o[7] = (short)f2bf(u1.w);
    return o;
}

// ---- K1: global bucket build (1 load + 1 atomic + 1 store per sample) ----
__global__ void k_bucket(const int* __restrict__ tgt, int* __restrict__ cnt,
                         int* __restrict__ list2d, int N) {
    int i = blockIdx.x * blockDim.x + threadIdx.x;
    if (i < N) {
        int t = tgt[i];
        int pos = atomicAdd(&cnt[t], 1);
        if (pos < CAP) list2d[t * CAP + pos] = i;   // unordered; k_gram sorts
    }
}

// ---- K2: MFMA Gram + rolled prefix-product recurrence -> qb (kappa folded), w ----
// 512 blocks x 4 waves; wave owns one class. NO all-N scan; NO serial global
// gathers: recombination done from the register-resident MFMA fragments.
__global__ void __launch_bounds__(64 * CPB)
k_gram(const float* __restrict__ x, const int* __restrict__ tgt,
       const int* __restrict__ cnt, const int* __restrict__ list2d,
       const float* __restrict__ p_in, const float* __restrict__ kw,
       unsigned short* __restrict__ qb, float* __restrict__ w,
       int N, int C, float dval) {
    __shared__ int   slist[CPB][CAP];
    __shared__ float Graw[CPB][32][33];   // raw-row Gram; row/col 31 = P
    __shared__ float invv[CPB][32];       // 1/max(||r_i||,1e-12)
    __shared__ float gamS[CPB][CAP];      // gamma coefficients (scale raw rows)
    int tid = threadIdx.x, b = blockIdx.x;
    int lane = tid & 63, wv = tid >> 6;
    int c = b * CPB + wv, e = lane & 31;

    int n = cnt[c];
    float kap = fmaxf(kw[c], 0.0f);

    if (n <= CAP) {
        // ---- Phase B: rank-sort this class's bucket (ascending) into slist ----
        int idx = (lane < n) ? list2d[c * CAP + lane] : 0x7fffffff;
        int rank = 0;
        for (int j = 0; j < n; ++j) { int v = __shfl(idx, j); rank += (v < idx) ? 1 : 0; }
        if (lane < n) slist[wv][rank] = idx;

        // ---- Phase C: fragment gather (rows 0..n-1 raw samples, 31 raw P) + 4 MFMAs ----
        int m = lane & 15, kg = lane >> 4, k0 = kg * 8;
        short8v A0 = {0,0,0,0,0,0,0,0}, A1 = {0,0,0,0,0,0,0,0};
        if (m < n) {
            const float4* px = (const float4*)(x + (size_t)slist[wv][m] * D + k0);
            A0 = cvt8(px[0], px[1]);
        }
        {
            int r = 16 + m;
            if (r < n) {
                const float4* px = (const float4*)(x + (size_t)slist[wv][r] * D + k0);
                A1 = cvt8(px[0], px[1]);
            } else if (r == 31) {
                const float4* px = (const float4*)(p_in + (size_t)c * D + k0);
                A1 = cvt8(px[0], px[1]);
            }
        }
        float4v z = {0.f, 0.f, 0.f, 0.f};
        float4v g00 = __builtin_amdgcn_mfma_f32_16x16x32_bf16(A0, A0, z, 0, 0, 0);
        float4v g01 = __builtin_amdgcn_mfma_f32_16x16x32_bf16(A0, A1, z, 0, 0, 0);
        float4v g10 = __builtin_amdgcn_mfma_f32_16x16x32_bf16(A1, A0, z, 0, 0, 0);
        float4v g11 = __builtin_amdgcn_mfma_f32_16x16x32_bf16(A1, A1, z, 0, 0, 0);
#pragma unroll
        for (int r = 0; r < 4; ++r) {          // C/D: row=(lane>>4)*4+r, col=lane&15
            int rr = kg * 4 + r;
            Graw[wv][rr][m]           = g00[r];
            Graw[wv][rr][16 + m]      = g01[r];
            Graw[wv][16 + rr][m]      = g10[r];
            Graw[wv][16 + rr][16 + m] = g11[r];
        }
        if (lane < 32)
            invv[wv][lane] = 1.0f / fmaxf(sqrtf(Graw[wv][lane][lane]), 1e-12f);

        // ---- Phase D: rolled scalar recurrence (replicated on lanes; verified R16) ----
        float B = 1.0f, U2 = Graw[wv][31][31];
        for (int kk = 0; kk < n; ++kk) {
            const float* grow = &Graw[wv][kk][0];
            float a0 = 0.f, a1 = 0.f, a2 = 0.f, a3 = 0.f;
            int j = 0;
            for (; j + 4 <= kk; j += 4) {
                a0 = fmaf(gamS[wv][j],     grow[j],     a0);
                a1 = fmaf(gamS[wv][j + 1], grow[j + 1], a1);
                a2 = fmaf(gamS[wv][j + 2], grow[j + 2], a2);
                a3 = fmaf(gamS[wv][j + 3], grow[j + 3], a3);
            }
            for (; j < kk; ++j) a0 = fmaf(gamS[wv][j], grow[j], a0);
            float dot = grow[31] + ((a0 + a1) + (a2 + a3));
            float dsum = invv[wv][kk] * B * dot;
            float m2 = 0.0025f + fmaf(0.9025f, U2, 0.095f * dsum);
            float mm = fmaxf(sqrtf(m2), 1e-12f);
            B *= 0.95f / mm;                        // B_{k+1}
            float gk = (0.05f * invv[wv][kk]) / (mm * B);
            if (lane == 0) gamS[wv][kk] = gk;
            U2 = 1.0f;
        }

        // ---- Phase E: recombine from the held fragments (no memory on the path) ----
        // u[k] = P[k] + sum_j gamma_j r_j[k]; lane (m,kg) holds rows m and 16+m,
        // cols k0..k0+7. coef(A1 row 31) = 1.0 picks up P.
        float coef0 = (m < n) ? gamS[wv][m] : 0.0f;
        float coef1 = (16 + m < n) ? gamS[wv][16 + m] : ((16 + m == 31) ? 1.0f : 0.0f);
        float part[8];
#pragma unroll
        for (int jj = 0; jj < 8; ++jj)
            part[jj] = fmaf(coef0, bf2f((unsigned short)A0[jj]),
                            coef1 * bf2f((unsigned short)A1[jj]));
        // reduce over the 16 lanes (m) within each kg group
#pragma unroll
        for (int off = 1; off < 16; off <<= 1) {
#pragma unroll
            for (int jj = 0; jj < 8; ++jj)
                part[jj] += __shfl_xor(part[jj], off);
        }
        // sum of squares across all 32 k (groups hold disjoint k-ranges)
        float ssl = 0.f;
#pragma unroll
        for (int jj = 0; jj < 8; ++jj) ssl = fmaf(part[jj], part[jj], ssl);
        ssl += __shfl_xor(ssl, 16);
        ssl += __shfl_xor(ssl, 32);
        float pninv = 1.0f / fmaxf(sqrtf(ssl), 1e-8f);
        float sc = kap * pninv;
        if (m == 0) {
            short8v ov;
#pragma unroll
            for (int jj = 0; jj < 8; ++jj) ov[jj] = (short)f2bf(sc * part[jj]);
            *(short8v*)(qb + (size_t)c * D + k0) = ov;
        }
    } else {
        // ---- exact fallback (statistically never): ordered ballot-scan chain ----
        float p = p_in[(size_t)c * D + e];
        for (int ii = 0; ii < N; ii += 64) {
            unsigned long long mb = __ballot(tgt[ii + lane] == c);
            while (mb) {
                int j = __ffsll(mb) - 1;
                mb &= (mb - 1);
                float v = x[(size_t)(ii + j) * D + e];
                float s2 = v * v;
                s2 += __shfl_xor(s2, 16); s2 += __shfl_xor(s2, 8); s2 += __shfl_xor(s2, 4);
                s2 += __shfl_xor(s2, 2);  s2 += __shfl_xor(s2, 1);
                float s = v / fmaxf(sqrtf(s2), 1e-12f);
                p = fmaf(0.05f, s, 0.95f * p);
                float pp = p * p;
                pp += __shfl_xor(pp, 16); pp += __shfl_xor(pp, 8); pp += __shfl_xor(pp, 4);
                pp += __shfl_xor(pp, 2);  pp += __shfl_xor(pp, 1);
                p = p / fmaxf(sqrtf(pp), 1e-12f);
            }
        }
        float pp = p * p;
        pp += __shfl_xor(pp, 16); pp += __shfl_xor(pp, 8); pp += __shfl_xor(pp, 4);
        pp += __shfl_xor(pp, 2);  pp += __shfl_xor(pp, 1);
        float pn = p / fmaxf(sqrtf(pp), 1e-8f);
        if (lane < D) qb[(size_t)c * D + e] = f2bf(kap * pn);
    }

    if (lane == 0) {
        // log C_d(kap), cancellation-free rearrangement
        float nu = 0.5f * dval - 1.0f;
        float zz = kap / nu, z2 = zz * zz;
        float sq = sqrtf(1.0f + z2);
        float t  = 1.0f / sq;
        float u1 = (3.0f * t - 5.0f * t * t * t) * (1.0f / 24.0f);
        float lw = dval * (-0.918938533204672742f)
                 + nu * (logf(nu) + log1pf(sq) - sq)
                 + 0.5f * logf(6.2831853071795864f * nu)
                 + 0.25f * log1pf(z2)
                 - log1pf(u1 / nu);
        w[c] = __expf(lw);
    }
}

// ---- K3: per-block full-row MFMA + exp rowsum + target-logit capture + NLL ----
// (unchanged, verified) 1024 blocks x 8 waves; block owns 16 samples.
__global__ void __launch_bounds__(SBT)
k_score(const float* __restrict__ x, const int* __restrict__ tgt,
        const unsigned short* __restrict__ qb, const float* __restrict__ w,
        float* __restrict__ part, int N, int C) {
    __shared__ float Sl[8][SSM];
    __shared__ float Lt[SSM];
    int tid = threadIdx.x, b = blockIdx.x;
    int lane = tid & 63, wv = tid >> 6;
    int m = lane & 15, kg = lane >> 4, k0 = kg * 8;
    int s0 = b * SSM;

    short8v a0;
    {
        const float4* px = (const float4*)(x + (size_t)(s0 + m) * D + k0);
        float4 u0 = px[0], u1 = px[1];
        float ss = u0.x*u0.x + u0.y*u0.y + u0.z*u0.z + u0.w*u0.w
                 + u1.x*u1.x + u1.y*u1.y + u1.z*u1.z + u1.w*u1.w;
        ss += __shfl_xor(ss, 16); ss += __shfl_xor(ss, 32);
        float inv = 1.0f / fmaxf(sqrtf(ss), 1e-8f);
        float4 v0, v1;
        v0.x = u0.x*inv; v0.y = u0.y*inv; v0.z = u0.z*inv; v0.w = u0.w*inv;
        v1.x = u1.x*inv; v1.y = u1.y*inv; v1.z = u1.z*inv; v1.w = u1.w*inv;
        a0 = cvt8(v0, v1);
    }

    int tr0[4];
#pragma unroll
    for (int r = 0; r < 4; ++r) tr0[r] = tgt[s0 + kg * 4 + r];

    float4v z = {0.f, 0.f, 0.f, 0.f};
    float4v sa0 = z;
    int ntiles = C >> 7;
    for (int jt = 0; jt < ntiles; ++jt) {
        int c0 = (wv * ntiles + jt) * 16;
        short8v bfrag = *(const short8v*)(qb + (size_t)(c0 + m) * D + k0);
        float wl = w[c0 + m];
        float4v acc0 = __builtin_amdgcn_mfma_f32_16x16x32_bf16(a0, bfrag, z, 0, 0, 0);
#pragma unroll
        for (int r = 0; r < 4; ++r) {
            if (c0 + m == tr0[r]) Lt[kg * 4 + r] = acc0[r];
            sa0[r] = fmaf(wl, __expf(acc0[r]), sa0[r]);
        }
    }
#pragma unroll
    for (int off = 1; off < 16; off <<= 1) {
#pragma unroll
        for (int r = 0; r < 4; ++r) sa0[r] += __shfl_xor(sa0[r], off);
    }
    if (m == 0) {
#pragma unroll
        for (int r = 0; r < 4; ++r) Sl[wv][kg * 4 + r] = sa0[r];
    }
    __syncthreads();

    if (wv == 0) {
        float val = 0.f;
        if (lane < SSM) {
            int s = lane;
            float S = ((Sl[0][s] + Sl[1][s]) + (Sl[2][s] + Sl[3][s]))
                    + ((Sl[4][s] + Sl[5][s]) + (Sl[6][s] + Sl[7][s]));
            int t = tgt[s0 + s];
            val = logf(w[t] * __expf(Lt[s]) / S + 1e-6f);
        }
        val += __shfl_xor(val, 32); val += __shfl_xor(val, 16); val += __shfl_xor(val, 8);
        val += __shfl_xor(val, 4);  val += __shfl_xor(val, 2);  val += __shfl_xor(val, 1);
        if (lane == 0) part[b] = val;
    }
}

// ---- K4: deterministic fixed-order final reduce (1 block, 1024 partials) ----
__global__ void k_out(const float* __restrict__ part, float* __restrict__ out,
                      int N, int nblk) {
    __shared__ float red[8];
    int tid = threadIdx.x, lane = tid & 63, wv = tid >> 6;
    float v = 0.f;
    if (tid < nblk)       v += part[tid];
    if (tid + 512 < nblk) v += part[tid + 512];
    v += __shfl_xor(v, 32); v += __shfl_xor(v, 16); v += __shfl_xor(v, 8);
    v += __shfl_xor(v, 4);  v += __shfl_xor(v, 2);  v += __shfl_xor(v, 1);
    if (lane == 0) red[wv] = v;
    __syncthreads();
    if (tid == 0)
        out[0] = -(((red[0] + red[1]) + (red[2] + red[3]))
                 + ((red[4] + red[5]) + (red[6] + red[7]))) / (float)N;
}

extern "C" void kernel_launch(void* const* d_in, const int* in_sizes, int n_in,
                              void* d_out, int out_size, void* d_ws, size_t ws_size,
                              hipStream_t stream) {
    const float* x    = (const float*)d_in[0];   // [N, D]
    const float* kw   = (const float*)d_in[1];   // [C]
    const float* p_in = (const float*)d_in[2];   // [C, D]
    const int*   tgt  = (const int*)d_in[3];     // [N]
    int C = in_sizes[1];
    int N = in_sizes[3];
    float dval = (float)(in_sizes[2] / C);       // == 32
    int nblk = N / SSM;                           // 1024 score blocks

    // ws layout: cnt (zeroed) | list2d | qb | w | part
    int* cnt    = (int*)d_ws;                               // C ints
    int* list2d = cnt + C;                                  // C*CAP ints
    unsigned short* qb = (unsigned short*)(list2d + (size_t)C * CAP);  // C*D bf16
    float* w    = (float*)(qb + (size_t)C * D);             // C f32
    float* part = w + C;                                    // nblk f32
    (void)n_in; (void)out_size; (void)ws_size;

    // node 1: zero cnt (every replay)
    hipMemsetAsync(cnt, 0, (size_t)C * sizeof(int), stream);
    // node 2: global bucket build
    k_bucket<<<(N + 255) / 256, 256, 0, stream>>>(tgt, cnt, list2d, N);
    // node 3: MFMA-Gram solve -> qb, w  (no all-N scans, no serial gathers)
    k_gram<<<C / CPB, 64 * CPB, 0, stream>>>(x, tgt, cnt, list2d, p_in, kw, qb, w, N, C, dval);
    // node 4: full-row score + NLL partials
    k_score<<<nblk, SBT, 0, stream>>>(x, tgt, qb, w, part, N, C);
    // node 5: final reduce
    k_out<<<1, 512, 0, stream>>>(part, (float*)d_out, N, nblk);
}